// Round 1
// baseline (1668.481 us; speedup 1.0000x reference)
//
#include <hip/hip_runtime.h>
#include <cstdint>
#include <cstddef>

// ---------------------------------------------------------------------------
// GATFuse: 3x shared-weight GATConv layers on two edge sets + BN/ReLU,
// final GATConv (H=1), mean-fuse, linear readout, per-graph mean.
// Strategy: build dst-CSR per edge set once per call; all segment ops become
// per-node wave reductions (no atomics in hot paths).
// ---------------------------------------------------------------------------

#define NLAYERS 3

__device__ __forceinline__ float lrelu(float a){ return a > 0.f ? a : 0.2f*a; }

__device__ __forceinline__ float wsum(float v){
#pragma unroll
  for (int o = 32; o > 0; o >>= 1) v += __shfl_xor(v, o);
  return v;
}
__device__ __forceinline__ float wmaxr(float v){
#pragma unroll
  for (int o = 32; o > 0; o >>= 1) v = fmaxf(v, __shfl_xor(v, o));
  return v;
}
__device__ __forceinline__ int rdl_i(int v, int l){ return __builtin_amdgcn_readlane(v, l); }
__device__ __forceinline__ float rdl_f(float v, int l){
  return __uint_as_float(__builtin_amdgcn_readlane(__float_as_uint(v), l));
}

// ----------------------------- utility kernels -----------------------------
__global__ void zero_k(int* __restrict__ p, int n){
  int i = blockIdx.x*blockDim.x + threadIdx.x;
  if (i < n) p[i] = 0;
}
__global__ void copy_k(const int* __restrict__ a, int* __restrict__ b, int n){
  int i = blockIdx.x*blockDim.x + threadIdx.x;
  if (i < n) b[i] = a[i];
}
__global__ void count_k(const int* __restrict__ dst, int E, int* __restrict__ cnt){
  int e = blockIdx.x*blockDim.x + threadIdx.x;
  if (e < E) atomicAdd(&cnt[dst[e]], 1);
}
__global__ __launch_bounds__(1024) void scanA_k(const int* __restrict__ cnt,
    int* __restrict__ excl, int* __restrict__ bsum, int N){
  __shared__ int wpart[16];
  const int tid = threadIdx.x, lane = tid & 63, w = tid >> 6;
  const int i = blockIdx.x*1024 + tid;
  const int v = (i < N) ? cnt[i] : 0;
  int s = v;
#pragma unroll
  for (int o = 1; o < 64; o <<= 1){ int t = __shfl_up(s, o); if (lane >= o) s += t; }
  if (lane == 63) wpart[w] = s;
  __syncthreads();
  if (w == 0){
    int t = (lane < 16) ? wpart[lane] : 0;
#pragma unroll
    for (int o = 1; o < 16; o <<= 1){ int u = __shfl_up(t, o); if (lane >= o) t += u; }
    if (lane < 16) wpart[lane] = t;
  }
  __syncthreads();
  const int woff = (w > 0) ? wpart[w-1] : 0;
  const int incl = s + woff;
  if (i < N) excl[i] = incl - v;
  if (tid == 1023) bsum[blockIdx.x] = incl;
}
__global__ void scanB_k(const int* __restrict__ bsum, int* __restrict__ boff, int nb){
  const int lane = threadIdx.x;
  const int v = (lane < nb) ? bsum[lane] : 0;
  int s = v;
#pragma unroll
  for (int o = 1; o < 64; o <<= 1){ int t = __shfl_up(s, o); if (lane >= o) s += t; }
  if (lane < nb) boff[lane] = s - v;
  if (lane == nb-1) boff[nb] = s;
}
__global__ __launch_bounds__(1024) void scanC_k(int* __restrict__ rp,
    const int* __restrict__ boff, int N, int nb){
  const int i = blockIdx.x*1024 + threadIdx.x;
  if (i < N) rp[i] += boff[blockIdx.x];
  if (i == 0) rp[N] = boff[nb];
}
__global__ void fill_k(const int* __restrict__ src, const int* __restrict__ dst, int E,
                       int* __restrict__ pos, int* __restrict__ col){
  int e = blockIdx.x*blockDim.x + threadIdx.x;
  if (e < E){
    int d = dst[e];
    int p = atomicAdd(&pos[d], 1);
    col[p] = src[e];
  }
}

// ----------------------------- GEMM  h = A(Nx128) @ W(128xM) ----------------
// 64x64 tile per 256-thread block; x staged transposed [k][row] with XOR
// swizzle (bits 2..5 by k>>2) so reads are b128 conflict-free.
__global__ __launch_bounds__(256) void gemm_k(const float* __restrict__ A,
    const float* __restrict__ W, float* __restrict__ O, int N, int M){
  __shared__ float xs[128][64];   // [k][swizzled row]
  __shared__ float wsh[128][64];  // [k][col]
  const int tid = threadIdx.x;
  const int row0 = blockIdx.x*64, col0 = blockIdx.y*64;
  {
    const int c4 = (tid & 15)*4;
#pragma unroll
    for (int p = 0; p < 8; ++p){
      const int k = p*16 + (tid >> 4);
      *reinterpret_cast<float4*>(&wsh[k][c4]) =
          *reinterpret_cast<const float4*>(&W[(size_t)k*M + col0 + c4]);
    }
    const int k4 = (tid & 31)*4;
    const int rbase = (tid >> 5);
#pragma unroll
    for (int p = 0; p < 8; ++p){
      const int rr = p*8 + rbase;
      int gr = row0 + rr; if (gr > N-1) gr = N-1;
      const float4 xv = *reinterpret_cast<const float4*>(&A[(size_t)gr*128 + k4]);
      const float xq[4] = {xv.x, xv.y, xv.z, xv.w};
#pragma unroll
      for (int q = 0; q < 4; ++q){
        const int k = k4 + q;
        const int swz = ((k >> 2) & 15) << 2;
        xs[k][rr ^ swz] = xq[q];
      }
    }
  }
  __syncthreads();
  const int ty = tid >> 4, tx = tid & 15;
  float acc[4][4] = {};
#pragma unroll 8
  for (int k = 0; k < 128; ++k){
    const int swz = ((k >> 2) & 15) << 2;
    const int xr = (ty*4) ^ swz;
    const float4 xv = *reinterpret_cast<const float4*>(&xs[k][xr]);
    const float2 w0 = *reinterpret_cast<const float2*>(&wsh[k][2*tx]);
    const float2 w1 = *reinterpret_cast<const float2*>(&wsh[k][32 + 2*tx]);
    const float xq[4] = {xv.x, xv.y, xv.z, xv.w};
#pragma unroll
    for (int i = 0; i < 4; ++i){
      acc[i][0] += xq[i]*w0.x;
      acc[i][1] += xq[i]*w0.y;
      acc[i][2] += xq[i]*w1.x;
      acc[i][3] += xq[i]*w1.y;
    }
  }
#pragma unroll
  for (int i = 0; i < 4; ++i){
    const int r = row0 + ty*4 + i;
    if (r < N){
      float2* o2 = reinterpret_cast<float2*>(&O[(size_t)r*M + col0]);
      o2[tx]      = make_float2(acc[i][0], acc[i][1]);
      o2[16 + tx] = make_float2(acc[i][2], acc[i][3]);
    }
  }
}

// ------------------------ attention logits per node -------------------------
template<int H>
__global__ __launch_bounds__(256) void alpha_k(const float* __restrict__ h,
    const float* __restrict__ asrc, const float* __restrict__ adst,
    float* __restrict__ als, float* __restrict__ ald, int N){
  const int lane = threadIdx.x & 63;
  const int n = blockIdx.x*4 + (threadIdx.x >> 6);
  if (n >= N) return;
  if (H == 2){
    const float h0 = h[(size_t)n*128 + lane];
    const float h1 = h[(size_t)n*128 + 64 + lane];
    const float s0 = wsum(h0*asrc[lane]);
    const float s1 = wsum(h1*asrc[64 + lane]);
    const float d0 = wsum(h0*adst[lane]);
    const float d1 = wsum(h1*adst[64 + lane]);
    if (lane == 0){
      ((float2*)als)[n] = make_float2(s0, s1);
      ((float2*)ald)[n] = make_float2(d0, d1);
    }
  } else {
    const float h0 = h[(size_t)n*64 + lane];
    const float s0 = wsum(h0*asrc[lane]);
    const float d0 = wsum(h0*adst[lane]);
    if (lane == 0){ als[n] = s0; ald[n] = d0; }
  }
}

// -------- per-node softmax over incoming edges + weighted gather-sum --------
template<int H>
__global__ __launch_bounds__(256) void agg_k(const float* __restrict__ h,
    const float* __restrict__ als, const float* __restrict__ ald,
    const int* __restrict__ rp, const int* __restrict__ col,
    const float* __restrict__ bias, float* __restrict__ out, int N){
  const int lane = threadIdx.x & 63;
  const int n = blockIdx.x*4 + (threadIdx.x >> 6);
  if (n >= N) return;
  const int beg = rp[n], end = rp[n+1];
  float as0, as1 = 0.f, ad0, ad1 = 0.f;
  if (H == 2){
    const float2 a = ((const float2*)als)[n];
    const float2 d = ((const float2*)ald)[n];
    as0 = a.x; as1 = a.y; ad0 = d.x; ad1 = d.y;
  } else { as0 = als[n]; ad0 = ald[n]; }
  const float self0 = lrelu(as0 + ad0);
  const float self1 = (H == 2) ? lrelu(as1 + ad1) : 0.f;
  float m0 = self0, m1 = self1;
  for (int i = beg + lane; i < end; i += 64){
    const int s = col[i];
    if (H == 2){
      const float2 a = ((const float2*)als)[s];
      m0 = fmaxf(m0, lrelu(a.x + ad0));
      m1 = fmaxf(m1, lrelu(a.y + ad1));
    } else m0 = fmaxf(m0, lrelu(als[s] + ad0));
  }
  m0 = wmaxr(m0); if (H == 2) m1 = wmaxr(m1);
  float p0 = 0.f, p1 = 0.f;
  for (int i = beg + lane; i < end; i += 64){
    const int s = col[i];
    if (H == 2){
      const float2 a = ((const float2*)als)[s];
      p0 += __expf(lrelu(a.x + ad0) - m0);
      p1 += __expf(lrelu(a.y + ad1) - m1);
    } else p0 += __expf(lrelu(als[s] + ad0) - m0);
  }
  p0 = wsum(p0) + __expf(self0 - m0);
  const float inv0 = 1.f/(p0 + 1e-16f);
  float inv1 = 0.f;
  if (H == 2){ p1 = wsum(p1) + __expf(self1 - m1); inv1 = 1.f/(p1 + 1e-16f); }

  if (H == 2){
    const float2* h2 = (const float2*)h;   // lane covers cols 2*lane, 2*lane+1
    const float csel = (lane < 32) ? __expf(self0 - m0)*inv0 : __expf(self1 - m1)*inv1;
    const float2 hv = h2[(size_t)n*64 + lane];
    float ax = csel*hv.x, ay = csel*hv.y;
    for (int base = beg; base < end; base += 64){
      const int idx = base + lane;
      int sv = 0; float c0v = 0.f, c1v = 0.f;
      if (idx < end){
        sv = col[idx];
        const float2 a = ((const float2*)als)[sv];
        c0v = __expf(lrelu(a.x + ad0) - m0)*inv0;
        c1v = __expf(lrelu(a.y + ad1) - m1)*inv1;
      }
      const int cnt = min(64, end - base);
      for (int j = 0; j < cnt; ++j){
        const int s = rdl_i(sv, j);
        const float c0 = rdl_f(c0v, j);
        const float c1 = rdl_f(c1v, j);
        const float c = (lane < 32) ? c0 : c1;
        const float2 hvv = h2[(size_t)s*64 + lane];
        ax += c*hvv.x; ay += c*hvv.y;
      }
    }
    const float2 bv = ((const float2*)bias)[lane];
    ((float2*)out)[(size_t)n*64 + lane] = make_float2(ax + bv.x, ay + bv.y);
  } else {
    const float csel = __expf(self0 - m0)*inv0;
    float a0 = csel*h[(size_t)n*64 + lane];
    for (int base = beg; base < end; base += 64){
      const int idx = base + lane;
      int sv = 0; float c0v = 0.f;
      if (idx < end){
        sv = col[idx];
        c0v = __expf(lrelu(als[sv] + ad0) - m0)*inv0;
      }
      const int cnt = min(64, end - base);
      for (int j = 0; j < cnt; ++j){
        const int s = rdl_i(sv, j);
        const float c = rdl_f(c0v, j);
        a0 += c*h[(size_t)s*64 + lane];
      }
    }
    out[(size_t)n*64 + lane] = a0 + bias[lane];
  }
}

// ------------------------------- batch norm ---------------------------------
__global__ __launch_bounds__(128) void bn_stats_k(const float* __restrict__ x, int N,
                                                  double* __restrict__ st){
  const int c = threadIdx.x;           // 128 columns
  double s = 0.0, s2 = 0.0;
  for (int r = blockIdx.x; r < N; r += gridDim.x){
    const float v = x[(size_t)r*128 + c];
    s += v; s2 += (double)v*(double)v;
  }
  atomicAdd(&st[c], s);
  atomicAdd(&st[128 + c], s2);
}
__global__ __launch_bounds__(128) void bn_apply_k(float* __restrict__ x,
    const double* __restrict__ st, const float* __restrict__ g,
    const float* __restrict__ b, int N){
  const int c = threadIdx.x;
  const float mu  = (float)(st[c]/(double)N);
  const float var = (float)(st[128 + c]/(double)N - (double)mu*(double)mu);
  const float sc = rsqrtf(var + 1e-5f)*g[c];
  const float sh = b[c];
  for (int r = blockIdx.x; r < N; r += gridDim.x){
    float v = x[(size_t)r*128 + c];
    v = (v - mu)*sc + sh;
    x[(size_t)r*128 + c] = fmaxf(v, 0.f);
  }
}

// ------------------------------ readout -------------------------------------
__global__ __launch_bounds__(256) void final_k(const float* __restrict__ f0,
    const float* __restrict__ f1, const float* __restrict__ Wo,
    const float* __restrict__ bo, const int* __restrict__ bid,
    float* __restrict__ gsum, float* __restrict__ gcnt, int N){
  const int lane = threadIdx.x & 63;
  const int n = blockIdx.x*4 + (threadIdx.x >> 6);
  if (n >= N) return;
  const float xf = (f0[(size_t)n*64 + lane] + f1[(size_t)n*64 + lane])*0.5f;
  const float p = wsum(xf*Wo[lane]);
  if (lane == 0){
    const int g = bid[n];
    atomicAdd(&gsum[g], p + bo[0]);
    atomicAdd(&gcnt[g], 1.f);
  }
}
__global__ void div_k(const float* __restrict__ gsum, const float* __restrict__ gcnt,
                      float* __restrict__ out, int G){
  const int i = blockIdx.x*blockDim.x + threadIdx.x;
  if (i < G) out[i] = gsum[i]/fmaxf(gcnt[i], 1.f);
}

// ---------------------------------------------------------------------------
extern "C" void kernel_launch(void* const* d_in, const int* in_sizes, int n_in,
                              void* d_out, int out_size, void* d_ws, size_t ws_size,
                              hipStream_t stream) {
  const int N = in_sizes[0]/128;      // 50000
  const int E = in_sizes[1]/2;        // 800000
  const int G = out_size;             // 512

  const float* x    = (const float*)d_in[0];
  const int*   eisc = (const int*)d_in[1];
  const int*   eifc = (const int*)d_in[2];
  const int*   bid  = (const int*)d_in[3];
  const float* Ws   = (const float*)d_in[4];
  const float* atts = (const float*)d_in[5];
  const float* attd = (const float*)d_in[6];
  const float* bgat = (const float*)d_in[7];
  const float* bng  = (const float*)d_in[8];
  const float* bnb  = (const float*)d_in[9];
  const float* Wf   = (const float*)d_in[10];
  const float* afs  = (const float*)d_in[11];
  const float* afd  = (const float*)d_in[12];
  const float* bf   = (const float*)d_in[13];
  const float* Wo   = (const float*)d_in[14];
  const float* bo   = (const float*)d_in[15];
  float* out = (float*)d_out;

  char* wp = (char*)d_ws;
  auto grab = [&](size_t bytes)->char* {
    uintptr_t p = ((uintptr_t)wp + 255) & ~(uintptr_t)255;
    wp = (char*)(p + bytes);
    return (char*)p;
  };
  // zeroed region (contiguous, single zero kernel)
  char* zbase = (char*)(((uintptr_t)d_ws + 255) & ~(uintptr_t)255);
  int*    cntA  = (int*)grab((size_t)N*4);
  int*    cntB  = (int*)grab((size_t)N*4);
  double* stats = (double*)grab((size_t)6*256*8);
  float*  gsum  = (float*)grab((size_t)G*4);
  float*  gcnt  = (float*)grab((size_t)G*4);
  const int zwords = (int)(((size_t)(wp - zbase)) / 4);
  // non-zeroed scratch
  int*   rp_sc  = (int*)grab((size_t)(N+1)*4);
  int*   rp_fc  = (int*)grab((size_t)(N+1)*4);
  int*   col_sc = (int*)grab((size_t)E*4);
  int*   col_fc = (int*)grab((size_t)E*4);
  int*   bsum   = (int*)grab(64*4);
  int*   boff   = (int*)grab(65*4);
  float* hb     = (float*)grab((size_t)N*128*4);
  float* x0b    = (float*)grab((size_t)N*128*4);
  float* x1b    = (float*)grab((size_t)N*128*4);
  float* alsb   = (float*)grab((size_t)N*2*4);
  float* aldb   = (float*)grab((size_t)N*2*4);
  (void)ws_size; (void)n_in;

  zero_k<<<(zwords + 255)/256, 256, 0, stream>>>((int*)zbase, zwords);

  const int EB = (E + 255)/256;
  const int SB = (N + 1023)/1024;     // 49
  // ---- CSR for sc edge set (dst-major) ----
  count_k<<<EB, 256, 0, stream>>>(eisc + E, E, cntA);
  count_k<<<EB, 256, 0, stream>>>(eifc + E, E, cntB);
  scanA_k<<<SB, 1024, 0, stream>>>(cntA, rp_sc, bsum, N);
  scanB_k<<<1, 64, 0, stream>>>(bsum, boff, SB);
  scanC_k<<<SB, 1024, 0, stream>>>(rp_sc, boff, N, SB);
  copy_k<<<(N + 255)/256, 256, 0, stream>>>(rp_sc, cntA, N);
  fill_k<<<EB, 256, 0, stream>>>(eisc, eisc + E, E, cntA, col_sc);
  // ---- CSR for fc edge set ----
  scanA_k<<<SB, 1024, 0, stream>>>(cntB, rp_fc, bsum, N);
  scanB_k<<<1, 64, 0, stream>>>(bsum, boff, SB);
  scanC_k<<<SB, 1024, 0, stream>>>(rp_fc, boff, N, SB);
  copy_k<<<(N + 255)/256, 256, 0, stream>>>(rp_fc, cntB, N);
  fill_k<<<EB, 256, 0, stream>>>(eifc, eifc + E, E, cntB, col_fc);

  const int NB4 = (N + 3)/4;          // wave-per-node grids
  const dim3 gg2((N + 63)/64, 2), gg1((N + 63)/64, 1);
  const float* cur0 = x;
  const float* cur1 = x;
  for (int l = 0; l < NLAYERS; ++l){
    const float* Wl = Ws + (size_t)l*128*128;
    // branch 0 (sc)
    gemm_k<<<gg2, 256, 0, stream>>>(cur0, Wl, hb, N, 128);
    alpha_k<2><<<NB4, 256, 0, stream>>>(hb, atts + l*128, attd + l*128, alsb, aldb, N);
    agg_k<2><<<NB4, 256, 0, stream>>>(hb, alsb, aldb, rp_sc, col_sc, bgat + l*128, x0b, N);
    bn_stats_k<<<512, 128, 0, stream>>>(x0b, N, stats + (l*2 + 0)*256);
    bn_apply_k<<<512, 128, 0, stream>>>(x0b, stats + (l*2 + 0)*256, bng + l*128, bnb + l*128, N);
    cur0 = x0b;
    // branch 1 (fc)
    gemm_k<<<gg2, 256, 0, stream>>>(cur1, Wl, hb, N, 128);
    alpha_k<2><<<NB4, 256, 0, stream>>>(hb, atts + l*128, attd + l*128, alsb, aldb, N);
    agg_k<2><<<NB4, 256, 0, stream>>>(hb, alsb, aldb, rp_fc, col_fc, bgat + l*128, x1b, N);
    bn_stats_k<<<512, 128, 0, stream>>>(x1b, N, stats + (l*2 + 1)*256);
    bn_apply_k<<<512, 128, 0, stream>>>(x1b, stats + (l*2 + 1)*256, bng + l*128, bnb + l*128, N);
    cur1 = x1b;
  }
  // final convs (H=1, C=64); outputs reuse x0b/x1b (dead after gemm reads them)
  gemm_k<<<gg1, 256, 0, stream>>>(cur0, Wf, hb, N, 64);
  alpha_k<1><<<NB4, 256, 0, stream>>>(hb, afs, afd, alsb, aldb, N);
  agg_k<1><<<NB4, 256, 0, stream>>>(hb, alsb, aldb, rp_sc, col_sc, bf, x0b, N);

  gemm_k<<<gg1, 256, 0, stream>>>(cur1, Wf, hb, N, 64);
  alpha_k<1><<<NB4, 256, 0, stream>>>(hb, afs, afd, alsb, aldb, N);
  agg_k<1><<<NB4, 256, 0, stream>>>(hb, alsb, aldb, rp_fc, col_fc, bf, x1b, N);

  // fuse + readout + per-graph mean
  final_k<<<NB4, 256, 0, stream>>>(x0b, x1b, Wo, bo, bid, gsum, gcnt, N);
  div_k<<<(G + 255)/256, 256, 0, stream>>>(gsum, gcnt, out, G);
}

// Round 4
// 1346.360 us; speedup vs baseline: 1.2393x; 1.2393x over previous
//
#include <hip/hip_runtime.h>
#include <cstdint>
#include <cstddef>

// ---------------------------------------------------------------------------
// GATFuse: 3x shared-weight GATConv layers on two edge sets + BN/ReLU,
// final GATConv (H=1), mean-fuse, linear readout, per-graph mean.
// R1 -> R2 changes:
//  - readout: atomics replaced by per-node pred buffer + sorted-segment reduce
//  - BN apply+ReLU fused into next GEMM's A staging (bnfin_k makes scale/shift)
//  - alpha (att_src/att_dst dots) fused into GEMM epilogue (per-head col block)
//  - layer-0 GEMM deduplicated (both branches share x and W[0])
//  - agg softmax: online (max,sum) single pass over incoming edges
// ---------------------------------------------------------------------------

#define NLAYERS 3

__device__ __forceinline__ float lrelu(float a){ return a > 0.f ? a : 0.2f*a; }

__device__ __forceinline__ float wsum(float v){
#pragma unroll
  for (int o = 32; o > 0; o >>= 1) v += __shfl_xor(v, o);
  return v;
}
__device__ __forceinline__ int rdl_i(int v, int l){ return __builtin_amdgcn_readlane(v, l); }
__device__ __forceinline__ float rdl_f(float v, int l){
  return __uint_as_float(__builtin_amdgcn_readlane(__float_as_uint(v), l));
}

// ----------------------------- utility kernels -----------------------------
__global__ void zero_k(int* __restrict__ p, int n){
  int i = blockIdx.x*blockDim.x + threadIdx.x;
  if (i < n) p[i] = 0;
}
__global__ void copy_k(const int* __restrict__ a, int* __restrict__ b, int n){
  int i = blockIdx.x*blockDim.x + threadIdx.x;
  if (i < n) b[i] = a[i];
}
__global__ void count_k(const int* __restrict__ dst, int E, int* __restrict__ cnt){
  int e = blockIdx.x*blockDim.x + threadIdx.x;
  if (e < E) atomicAdd(&cnt[dst[e]], 1);
}
__global__ __launch_bounds__(1024) void scanA_k(const int* __restrict__ cnt,
    int* __restrict__ excl, int* __restrict__ bsum, int N){
  __shared__ int wpart[16];
  const int tid = threadIdx.x, lane = tid & 63, w = tid >> 6;
  const int i = blockIdx.x*1024 + tid;
  const int v = (i < N) ? cnt[i] : 0;
  int s = v;
#pragma unroll
  for (int o = 1; o < 64; o <<= 1){ int t = __shfl_up(s, o); if (lane >= o) s += t; }
  if (lane == 63) wpart[w] = s;
  __syncthreads();
  if (w == 0){
    int t = (lane < 16) ? wpart[lane] : 0;
#pragma unroll
    for (int o = 1; o < 16; o <<= 1){ int u = __shfl_up(t, o); if (lane >= o) t += u; }
    if (lane < 16) wpart[lane] = t;
  }
  __syncthreads();
  const int woff = (w > 0) ? wpart[w-1] : 0;
  const int incl = s + woff;
  if (i < N) excl[i] = incl - v;
  if (tid == 1023) bsum[blockIdx.x] = incl;
}
__global__ void scanB_k(const int* __restrict__ bsum, int* __restrict__ boff, int nb){
  const int lane = threadIdx.x;
  const int v = (lane < nb) ? bsum[lane] : 0;
  int s = v;
#pragma unroll
  for (int o = 1; o < 64; o <<= 1){ int t = __shfl_up(s, o); if (lane >= o) s += t; }
  if (lane < nb) boff[lane] = s - v;
  if (lane == nb-1) boff[nb] = s;
}
__global__ __launch_bounds__(1024) void scanC_k(int* __restrict__ rp,
    const int* __restrict__ boff, int N, int nb){
  const int i = blockIdx.x*1024 + threadIdx.x;
  if (i < N) rp[i] += boff[blockIdx.x];
  if (i == 0) rp[N] = boff[nb];
}
__global__ void fill_k(const int* __restrict__ src, const int* __restrict__ dst, int E,
                       int* __restrict__ pos, int* __restrict__ col){
  int e = blockIdx.x*blockDim.x + threadIdx.x;
  if (e < E){
    int d = dst[e];
    int p = atomicAdd(&pos[d], 1);
    col[p] = src[e];
  }
}

// ----------------------------- GEMM  h = A(Nx128) @ W(128xM) ----------------
// 64x64 tile per 256-thread block. Optionally applies BN(scale,shift)+ReLU to
// A elements while staging (fusing the previous layer's bn_apply). Epilogue
// computes the per-head attention dots (alpha fusion): block (.,y) owns head y
// entirely (cols y*64..y*64+63), so als/ald are exact — no atomics.
__global__ __launch_bounds__(256) void gemm_k(const float* __restrict__ A,
    const float* __restrict__ W, float* __restrict__ O,
    const float* __restrict__ bnsc, const float* __restrict__ bnsh,
    const float* __restrict__ atts, const float* __restrict__ attd,
    float* __restrict__ als, float* __restrict__ ald, int N, int M){
  __shared__ float xs[128][64];   // [k][swizzled row]
  __shared__ float wsh[128][64];  // [k][col]
  const int tid = threadIdx.x;
  const int row0 = blockIdx.x*64, col0 = blockIdx.y*64;
  const int HS = gridDim.y;       // heads == col blocks
  {
    const int c4 = (tid & 15)*4;
#pragma unroll
    for (int p = 0; p < 8; ++p){
      const int k = p*16 + (tid >> 4);
      *reinterpret_cast<float4*>(&wsh[k][c4]) =
          *reinterpret_cast<const float4*>(&W[(size_t)k*M + col0 + c4]);
    }
    const int k4 = (tid & 31)*4;
    const int rbase = (tid >> 5);
#pragma unroll
    for (int p = 0; p < 8; ++p){
      const int rr = p*8 + rbase;
      int gr = row0 + rr; if (gr > N-1) gr = N-1;
      float4 xv = *reinterpret_cast<const float4*>(&A[(size_t)gr*128 + k4]);
      float xq[4] = {xv.x, xv.y, xv.z, xv.w};
      if (bnsc != nullptr){
#pragma unroll
        for (int q = 0; q < 4; ++q)
          xq[q] = fmaxf(xq[q]*bnsc[k4 + q] + bnsh[k4 + q], 0.f);
      }
#pragma unroll
      for (int q = 0; q < 4; ++q){
        const int k = k4 + q;
        const int swz = ((k >> 2) & 15) << 2;
        xs[k][rr ^ swz] = xq[q];
      }
    }
  }
  __syncthreads();
  const int ty = tid >> 4, tx = tid & 15;
  float acc[4][4] = {};
#pragma unroll 8
  for (int k = 0; k < 128; ++k){
    const int swz = ((k >> 2) & 15) << 2;
    const int xr = (ty*4) ^ swz;
    const float4 xv = *reinterpret_cast<const float4*>(&xs[k][xr]);
    const float2 w0 = *reinterpret_cast<const float2*>(&wsh[k][2*tx]);
    const float2 w1 = *reinterpret_cast<const float2*>(&wsh[k][32 + 2*tx]);
    const float xq[4] = {xv.x, xv.y, xv.z, xv.w};
#pragma unroll
    for (int i = 0; i < 4; ++i){
      acc[i][0] += xq[i]*w0.x;
      acc[i][1] += xq[i]*w0.y;
      acc[i][2] += xq[i]*w1.x;
      acc[i][3] += xq[i]*w1.y;
    }
  }
  // ---- alpha epilogue: per-head dots with att_src/att_dst ----
  {
    const float* as = atts + col0;   // head = blockIdx.y, 64 coeffs
    const float* ad = attd + col0;
    const float a_s0 = as[2*tx],      a_s1 = as[2*tx + 1];
    const float a_s2 = as[32 + 2*tx], a_s3 = as[33 + 2*tx];
    const float a_d0 = ad[2*tx],      a_d1 = ad[2*tx + 1];
    const float a_d2 = ad[32 + 2*tx], a_d3 = ad[33 + 2*tx];
#pragma unroll
    for (int i = 0; i < 4; ++i){
      float ps = acc[i][0]*a_s0 + acc[i][1]*a_s1 + acc[i][2]*a_s2 + acc[i][3]*a_s3;
      float pd = acc[i][0]*a_d0 + acc[i][1]*a_d1 + acc[i][2]*a_d2 + acc[i][3]*a_d3;
#pragma unroll
      for (int o = 1; o < 16; o <<= 1){
        ps += __shfl_xor(ps, o);
        pd += __shfl_xor(pd, o);
      }
      const int r = row0 + ty*4 + i;
      if (tx == 0 && r < N){
        als[(size_t)r*HS + blockIdx.y] = ps;
        ald[(size_t)r*HS + blockIdx.y] = pd;
      }
    }
  }
#pragma unroll
  for (int i = 0; i < 4; ++i){
    const int r = row0 + ty*4 + i;
    if (r < N){
      float2* o2 = reinterpret_cast<float2*>(&O[(size_t)r*M + col0]);
      o2[tx]      = make_float2(acc[i][0], acc[i][1]);
      o2[16 + tx] = make_float2(acc[i][2], acc[i][3]);
    }
  }
}

// -------- per-node softmax over incoming edges + weighted gather-sum --------
// Online (max, sum) in one pass over edges; pass C does coef + row gather.
template<int H>
__global__ __launch_bounds__(256) void agg_k(const float* __restrict__ h,
    const float* __restrict__ als, const float* __restrict__ ald,
    const int* __restrict__ rp, const int* __restrict__ col,
    const float* __restrict__ bias, float* __restrict__ out, int N){
  const int lane = threadIdx.x & 63;
  const int n = blockIdx.x*4 + (threadIdx.x >> 6);
  if (n >= N) return;
  const int beg = rp[n], end = rp[n+1];
  float as0, as1 = 0.f, ad0, ad1 = 0.f;
  if (H == 2){
    const float2 a = ((const float2*)als)[n];
    const float2 d = ((const float2*)ald)[n];
    as0 = a.x; as1 = a.y; ad0 = d.x; ad1 = d.y;
  } else { as0 = als[n]; ad0 = ald[n]; }
  const float self0 = lrelu(as0 + ad0);
  const float self1 = (H == 2) ? lrelu(as1 + ad1) : 0.f;
  // online softmax state per lane; init with self-ref point (lane 0 carries mass)
  float m0 = self0, p0 = (lane == 0) ? 1.f : 0.f;
  float m1 = self1, p1 = (lane == 0) ? 1.f : 0.f;
  for (int i = beg + lane; i < end; i += 64){
    const int s = col[i];
    if (H == 2){
      const float2 a = ((const float2*)als)[s];
      const float al0 = lrelu(a.x + ad0);
      const float al1 = lrelu(a.y + ad1);
      if (al0 > m0){ p0 = p0*__expf(m0 - al0) + 1.f; m0 = al0; }
      else p0 += __expf(al0 - m0);
      if (al1 > m1){ p1 = p1*__expf(m1 - al1) + 1.f; m1 = al1; }
      else p1 += __expf(al1 - m1);
    } else {
      const float al0 = lrelu(als[s] + ad0);
      if (al0 > m0){ p0 = p0*__expf(m0 - al0) + 1.f; m0 = al0; }
      else p0 += __expf(al0 - m0);
    }
  }
  // combine (m,p) across the wave
#pragma unroll
  for (int o = 1; o < 64; o <<= 1){
    const float om0 = __shfl_xor(m0, o), op0 = __shfl_xor(p0, o);
    const float nm0 = fmaxf(m0, om0);
    p0 = p0*__expf(m0 - nm0) + op0*__expf(om0 - nm0); m0 = nm0;
    if (H == 2){
      const float om1 = __shfl_xor(m1, o), op1 = __shfl_xor(p1, o);
      const float nm1 = fmaxf(m1, om1);
      p1 = p1*__expf(m1 - nm1) + op1*__expf(om1 - nm1); m1 = nm1;
    }
  }
  const float inv0 = 1.f/(p0 + 1e-16f);
  const float inv1 = (H == 2) ? 1.f/(p1 + 1e-16f) : 0.f;

  if (H == 2){
    const float2* h2 = (const float2*)h;   // lane covers cols 2*lane, 2*lane+1
    const float csel = (lane < 32) ? __expf(self0 - m0)*inv0 : __expf(self1 - m1)*inv1;
    const float2 hv = h2[(size_t)n*64 + lane];
    float ax = csel*hv.x, ay = csel*hv.y;
    for (int base = beg; base < end; base += 64){
      const int idx = base + lane;
      int sv = 0; float c0v = 0.f, c1v = 0.f;
      if (idx < end){
        sv = col[idx];
        const float2 a = ((const float2*)als)[sv];
        c0v = __expf(lrelu(a.x + ad0) - m0)*inv0;
        c1v = __expf(lrelu(a.y + ad1) - m1)*inv1;
      }
      const int cnt = min(64, end - base);
      for (int j = 0; j < cnt; ++j){
        const int s = rdl_i(sv, j);
        const float c0 = rdl_f(c0v, j);
        const float c1 = rdl_f(c1v, j);
        const float c = (lane < 32) ? c0 : c1;
        const float2 hvv = h2[(size_t)s*64 + lane];
        ax += c*hvv.x; ay += c*hvv.y;
      }
    }
    const float2 bv = ((const float2*)bias)[lane];
    ((float2*)out)[(size_t)n*64 + lane] = make_float2(ax + bv.x, ay + bv.y);
  } else {
    const float csel = __expf(self0 - m0)*inv0;
    float a0 = csel*h[(size_t)n*64 + lane];
    for (int base = beg; base < end; base += 64){
      const int idx = base + lane;
      int sv = 0; float c0v = 0.f;
      if (idx < end){
        sv = col[idx];
        c0v = __expf(lrelu(als[sv] + ad0) - m0)*inv0;
      }
      const int cnt = min(64, end - base);
      for (int j = 0; j < cnt; ++j){
        const int s = rdl_i(sv, j);
        const float c = rdl_f(c0v, j);
        a0 += c*h[(size_t)s*64 + lane];
      }
    }
    out[(size_t)n*64 + lane] = a0 + bias[lane];
  }
}

// ------------------------------- batch norm ---------------------------------
__global__ __launch_bounds__(128) void bn_stats_k(const float* __restrict__ x, int N,
                                                  double* __restrict__ st){
  const int c = threadIdx.x;           // 128 columns
  double s = 0.0, s2 = 0.0;
  for (int r = blockIdx.x; r < N; r += gridDim.x){
    const float v = x[(size_t)r*128 + c];
    s += v; s2 += (double)v*(double)v;
  }
  atomicAdd(&st[c], s);
  atomicAdd(&st[128 + c], s2);
}
// finalize: per-column scale/shift so next consumer applies v*sc + sh, then relu
__global__ __launch_bounds__(128) void bnfin_k(const double* __restrict__ st,
    const float* __restrict__ g, const float* __restrict__ b,
    float* __restrict__ sc, float* __restrict__ sh, int N){
  const int c = threadIdx.x;
  const double mu  = st[c]/(double)N;
  const double var = st[128 + c]/(double)N - mu*mu;
  const float s = rsqrtf((float)var + 1e-5f)*g[c];
  sc[c] = s;
  sh[c] = b[c] - (float)mu*s;
}

// ------------------------------ readout -------------------------------------
__global__ __launch_bounds__(256) void pred_k(const float* __restrict__ f0,
    const float* __restrict__ f1, const float* __restrict__ Wo,
    float* __restrict__ pred, int N){
  const int lane = threadIdx.x & 63;
  const int n = blockIdx.x*4 + (threadIdx.x >> 6);
  if (n >= N) return;
  const float xf = (f0[(size_t)n*64 + lane] + f1[(size_t)n*64 + lane])*0.5f;
  const float p = wsum(xf*Wo[lane]);
  if (lane == 0) pred[n] = p;
}
// sorted-segment mean over graphs: one wave per graph, binary-search bounds
__global__ __launch_bounds__(64) void segred_k(const float* __restrict__ pred,
    const int* __restrict__ bid, const float* __restrict__ bo,
    float* __restrict__ out, int N){
  const int g = blockIdx.x;
  int lo = 0, hi = N;
  while (lo < hi){ const int mid = (lo + hi) >> 1; if (bid[mid] < g) lo = mid + 1; else hi = mid; }
  const int s0 = lo;
  hi = N;
  while (lo < hi){ const int mid = (lo + hi) >> 1; if (bid[mid] < g + 1) lo = mid + 1; else hi = mid; }
  const int s1 = lo;
  float s = 0.f;
  for (int i = s0 + threadIdx.x; i < s1; i += 64) s += pred[i];
  s = wsum(s);
  if (threadIdx.x == 0)
    out[g] = (s1 > s0) ? s/(float)(s1 - s0) + bo[0] : 0.f;
}

// ---------------------------------------------------------------------------
extern "C" void kernel_launch(void* const* d_in, const int* in_sizes, int n_in,
                              void* d_out, int out_size, void* d_ws, size_t ws_size,
                              hipStream_t stream) {
  const int N = in_sizes[0]/128;      // 50000
  const int E = in_sizes[1]/2;        // 800000
  const int G = out_size;             // 512

  const float* x    = (const float*)d_in[0];
  const int*   eisc = (const int*)d_in[1];
  const int*   eifc = (const int*)d_in[2];
  const int*   bid  = (const int*)d_in[3];
  const float* Ws   = (const float*)d_in[4];
  const float* atts = (const float*)d_in[5];
  const float* attd = (const float*)d_in[6];
  const float* bgat = (const float*)d_in[7];
  const float* bng  = (const float*)d_in[8];
  const float* bnb  = (const float*)d_in[9];
  const float* Wf   = (const float*)d_in[10];
  const float* afs  = (const float*)d_in[11];
  const float* afd  = (const float*)d_in[12];
  const float* bf   = (const float*)d_in[13];
  const float* Wo   = (const float*)d_in[14];
  const float* bo   = (const float*)d_in[15];
  float* out = (float*)d_out;

  char* wp = (char*)d_ws;
  auto grab = [&](size_t bytes)->char* {
    uintptr_t p = ((uintptr_t)wp + 255) & ~(uintptr_t)255;
    wp = (char*)(p + bytes);
    return (char*)p;
  };
  // zeroed region (contiguous, single zero kernel)
  char* zbase = (char*)(((uintptr_t)d_ws + 255) & ~(uintptr_t)255);
  int*    cntA  = (int*)grab((size_t)N*4);
  int*    cntB  = (int*)grab((size_t)N*4);
  double* stats = (double*)grab((size_t)6*256*8);
  const int zwords = (int)(((size_t)(wp - zbase)) / 4);
  // non-zeroed scratch
  int*   rp_sc  = (int*)grab((size_t)(N+1)*4);
  int*   rp_fc  = (int*)grab((size_t)(N+1)*4);
  int*   col_sc = (int*)grab((size_t)E*4);
  int*   col_fc = (int*)grab((size_t)E*4);
  int*   bsum   = (int*)grab(64*4);
  int*   boff   = (int*)grab(65*4);
  float* hb     = (float*)grab((size_t)N*128*4);
  float* x0b    = (float*)grab((size_t)N*128*4);
  float* x1b    = (float*)grab((size_t)N*128*4);
  float* alsb   = (float*)grab((size_t)N*2*4);
  float* aldb   = (float*)grab((size_t)N*2*4);
  float* bnsc   = (float*)grab((size_t)6*128*4);
  float* bnsh   = (float*)grab((size_t)6*128*4);
  float* pred   = alsb;               // reuse (dead by readout time)
  (void)ws_size; (void)n_in;

  zero_k<<<(zwords + 255)/256, 256, 0, stream>>>((int*)zbase, zwords);

  const int EB = (E + 255)/256;
  const int SB = (N + 1023)/1024;     // 49
  // ---- CSR for sc edge set (dst-major) ----
  count_k<<<EB, 256, 0, stream>>>(eisc + E, E, cntA);
  count_k<<<EB, 256, 0, stream>>>(eifc + E, E, cntB);
  scanA_k<<<SB, 1024, 0, stream>>>(cntA, rp_sc, bsum, N);
  scanB_k<<<1, 64, 0, stream>>>(bsum, boff, SB);
  scanC_k<<<SB, 1024, 0, stream>>>(rp_sc, boff, N, SB);
  copy_k<<<(N + 255)/256, 256, 0, stream>>>(rp_sc, cntA, N);
  fill_k<<<EB, 256, 0, stream>>>(eisc, eisc + E, E, cntA, col_sc);
  // ---- CSR for fc edge set ----
  scanA_k<<<SB, 1024, 0, stream>>>(cntB, rp_fc, bsum, N);
  scanB_k<<<1, 64, 0, stream>>>(bsum, boff, SB);
  scanC_k<<<SB, 1024, 0, stream>>>(rp_fc, boff, N, SB);
  copy_k<<<(N + 255)/256, 256, 0, stream>>>(rp_fc, cntB, N);
  fill_k<<<EB, 256, 0, stream>>>(eifc, eifc + E, E, cntB, col_fc);

  const int NB4 = (N + 3)/4;          // wave-per-node grids
  const dim3 gg2((N + 63)/64, 2), gg1((N + 63)/64, 1);
  const float* cur0 = x;
  const float* cur1 = x;
  for (int l = 0; l < NLAYERS; ++l){
    const float* Wl = Ws + (size_t)l*128*128;
    const float* as = atts + l*128;
    const float* ad = attd + l*128;
    const float* bg = bgat + l*128;
    // BN params of PREVIOUS layer fused into this gemm's A staging (l==0: none)
    const float* sc0 = (l == 0) ? nullptr : bnsc + ((l-1)*2 + 0)*128;
    const float* sh0 = (l == 0) ? nullptr : bnsh + ((l-1)*2 + 0)*128;
    const float* sc1 = (l == 0) ? nullptr : bnsc + ((l-1)*2 + 1)*128;
    const float* sh1 = (l == 0) ? nullptr : bnsh + ((l-1)*2 + 1)*128;

    // branch 0 (sc)
    gemm_k<<<gg2, 256, 0, stream>>>(cur0, Wl, hb, sc0, sh0, as, ad, alsb, aldb, N, 128);
    agg_k<2><<<NB4, 256, 0, stream>>>(hb, alsb, aldb, rp_sc, col_sc, bg, x0b, N);
    bn_stats_k<<<512, 128, 0, stream>>>(x0b, N, stats + (l*2 + 0)*256);
    bnfin_k<<<1, 128, 0, stream>>>(stats + (l*2 + 0)*256, bng + l*128, bnb + l*128,
                                   bnsc + (l*2 + 0)*128, bnsh + (l*2 + 0)*128, N);
    // branch 1 (fc): layer 0 shares x AND W -> reuse hb/alsb/aldb from branch 0
    if (l != 0)
      gemm_k<<<gg2, 256, 0, stream>>>(cur1, Wl, hb, sc1, sh1, as, ad, alsb, aldb, N, 128);
    agg_k<2><<<NB4, 256, 0, stream>>>(hb, alsb, aldb, rp_fc, col_fc, bg, x1b, N);
    bn_stats_k<<<512, 128, 0, stream>>>(x1b, N, stats + (l*2 + 1)*256);
    bnfin_k<<<1, 128, 0, stream>>>(stats + (l*2 + 1)*256, bng + l*128, bnb + l*128,
                                   bnsc + (l*2 + 1)*128, bnsh + (l*2 + 1)*128, N);
    cur0 = x0b;
    cur1 = x1b;
  }
  // final convs (H=1, C=64); BN of layer 2 fused into gemm A staging.
  // agg outputs reuse x0b/x1b as [N][64] (safe: gemm consumed them already).
  gemm_k<<<gg1, 256, 0, stream>>>(cur0, Wf, hb, bnsc + 4*128, bnsh + 4*128,
                                  afs, afd, alsb, aldb, N, 64);
  agg_k<1><<<NB4, 256, 0, stream>>>(hb, alsb, aldb, rp_sc, col_sc, bf, x0b, N);

  gemm_k<<<gg1, 256, 0, stream>>>(cur1, Wf, hb, bnsc + 5*128, bnsh + 5*128,
                                  afs, afd, alsb, aldb, N, 64);
  agg_k<1><<<NB4, 256, 0, stream>>>(hb, alsb, aldb, rp_fc, col_fc, bf, x1b, N);

  // fuse + readout + per-graph mean (atomic-free: sorted-segment reduce)
  pred_k<<<NB4, 256, 0, stream>>>(x0b, x1b, Wo, pred, N);
  segred_k<<<G, 64, 0, stream>>>(pred, bid, bo, out, N);
}